// Round 4
// baseline (282.763 us; speedup 1.0000x reference)
//
#include <hip/hip_runtime.h>
#include <math.h>

// PCATemplateMap: x (64,2048,19,19) f32, templates (10,19,19) f32
// outputs: mask (64,1,19,19) then v (64,10), concatenated flat.
//
//  k1 (wave-per-channel, coalesced): lanes split the 361-float row; template
//     fragments live in registers; Q via shfl_xor butterfly; one-hot-mask
//     select maps lanes to the 65 S1/S2 slots; block partials -> d_ws.
//  k2: one wave per batch. D = S2 - S1 S1^T / C, faithful fp32 LAPACK ssyevd
//     (ssytd2 LDS + ssteqr in lane-distributed registers via readlane +
//     argmax + single-column sormtr) -> v, mask.

#define NB   64
#define NC   2048
#define NHW  361
#define NTMP 10

struct f4 { float x, y, z, w; };
__device__ inline f4 load4u(const float* p){
    f4 r;
    __builtin_memcpy(&r, p, 16);
    return r;
}

__device__ inline float rl(float v, int i){
    return __int_as_float(__builtin_amdgcn_readlane(__float_as_int(v), i));
}

// ======================= Kernel 1: partial S1/S2 ==========================
// grid: NB*CBLK blocks, 256 threads (4 waves). Wave handles CPW channels.
template<int CBLK>
__global__ __launch_bounds__(256, 2) void k1_partials(
        const float* __restrict__ x, const float* __restrict__ tmpl,
        float* __restrict__ partial)
{
    constexpr int CPW = NC / CBLK / 4;     // channels per wave (even)
    __shared__ __align__(16) float Tl[NTMP][368];
    __shared__ float red[4][66];
    const int tid = threadIdx.x, lane = tid & 63, wid = tid >> 6;

    for (int idx = tid; idx < NTMP*368; idx += 256){
        int t = idx / 368, i = idx - t*368;
        Tl[t][i] = (i < NHW) ? tmpl[t*NHW + i] : 0.f;
    }
    __syncthreads();

    // ---- per-lane loop-invariant template fragments (registers) ----
    const int off1 = 4*lane;                                    // i 0..255
    const int off2 = (lane < 26) ? 256 + 4*lane                 // i 256..359
                   : ((lane == 26) ? 357 : 256);                // 357..360 / dummy
    float tv1[NTMP][4], tv2[NTMP][4];
    #pragma unroll
    for (int t = 0; t < NTMP; t++){
        const f4 a = *reinterpret_cast<const f4*>(&Tl[t][off1]);
        tv1[t][0]=a.x; tv1[t][1]=a.y; tv1[t][2]=a.z; tv1[t][3]=a.w;
        if (lane < 26){
            const f4 c = *reinterpret_cast<const f4*>(&Tl[t][off2]);
            tv2[t][0]=c.x; tv2[t][1]=c.y; tv2[t][2]=c.z; tv2[t][3]=c.w;
        } else if (lane == 26){
            tv2[t][0]=0.f; tv2[t][1]=0.f; tv2[t][2]=0.f; tv2[t][3]=Tl[t][360];
        } else {
            tv2[t][0]=0.f; tv2[t][1]=0.f; tv2[t][2]=0.f; tv2[t][3]=0.f;
        }
    }

    // ---- lane -> S-slot mapping (one-hot masks; no runtime reg indexing) --
    int tA, uA;
    if (lane < 55){
        int k = lane, t = 0;
        while (k >= NTMP - t){ k -= NTMP - t; t++; }
        tA = t; uA = t + k;
    } else { tA = lane - 55; uA = tA; }
    float mA[NTMP], mB[NTMP];
    #pragma unroll
    for (int t = 0; t < NTMP; t++){
        mA[t] = (tA == t) ? 1.f : 0.f;
        mB[t] = (uA == t) ? 1.f : 0.f;
    }
    const float fS1 = (lane >= 55) ? 1.f : 0.f;   // lanes 55..63: S1[0..8]
    const float fS9 = (lane == 54) ? 1.f : 0.f;   // lane 54 also: S1[9]

    const int b  = blockIdx.x / CBLK;
    const int cb = blockIdx.x % CBLK;
    const int c0 = cb*(NC/CBLK) + wid*CPW;
    const float* xw = x + ((size_t)b*NC + c0)*NHW;

    float sv = 0.f, s1v = 0.f;

    // prefetch channels 0,1
    f4 a1 = load4u(xw + off1);
    f4 a2 = load4u(xw + off2);
    f4 b1 = load4u(xw + NHW + off1);
    f4 b2 = load4u(xw + NHW + off2);

    for (int ci = 0; ci < CPW/2; ci++){
        f4 n1 = a1, n2 = a2, n3 = b1, n4 = b2;
        if (ci < CPW/2 - 1){
            const float* xn = xw + (size_t)(2*ci + 2)*NHW;
            n1 = load4u(xn + off1);
            n2 = load4u(xn + off2);
            n3 = load4u(xn + NHW + off1);
            n4 = load4u(xn + NHW + off2);
        }
        // per-lane partial dots (8 FMA per template per channel)
        float qA[NTMP], qB[NTMP];
        #pragma unroll
        for (int t = 0; t < NTMP; t++){
            qA[t] = a1.x*tv1[t][0] + a1.y*tv1[t][1] + a1.z*tv1[t][2] + a1.w*tv1[t][3]
                  + a2.x*tv2[t][0] + a2.y*tv2[t][1] + a2.z*tv2[t][2] + a2.w*tv2[t][3];
            qB[t] = b1.x*tv1[t][0] + b1.y*tv1[t][1] + b1.z*tv1[t][2] + b1.w*tv1[t][3]
                  + b2.x*tv2[t][0] + b2.y*tv2[t][1] + b2.z*tv2[t][2] + b2.w*tv2[t][3];
        }
        // butterfly reduce across 64 lanes -> every lane holds full Q
        #pragma unroll
        for (int t = 0; t < NTMP; t++){
            float v = qA[t];
            v += __shfl_xor(v, 1);  v += __shfl_xor(v, 2);  v += __shfl_xor(v, 4);
            v += __shfl_xor(v, 8);  v += __shfl_xor(v, 16); v += __shfl_xor(v, 32);
            qA[t] = v;
            float w = qB[t];
            w += __shfl_xor(w, 1);  w += __shfl_xor(w, 2);  w += __shfl_xor(w, 4);
            w += __shfl_xor(w, 8);  w += __shfl_xor(w, 16); w += __shfl_xor(w, 32);
            qB[t] = w;
        }
        // one-hot select + accumulate
        float qa = 0.f, qb = 0.f, ra = 0.f, rb = 0.f;
        #pragma unroll
        for (int t = 0; t < NTMP; t++){
            qa += qA[t]*mA[t];  qb += qA[t]*mB[t];
            ra += qB[t]*mA[t];  rb += qB[t]*mB[t];
        }
        sv  += qa*qb + ra*rb;
        s1v += fS1*(qa + ra) + fS9*(qA[9] + qB[9]);
        a1 = n1; a2 = n2; b1 = n3; b2 = n4;
    }

    // ---- wave slots -> LDS -> block partial ----
    if (lane < 55) red[wid][10 + lane] = sv;
    else           red[wid][lane - 55] = s1v;
    if (lane == 54) red[wid][9] = s1v;
    __syncthreads();
    if (tid < 65){
        float v = red[0][tid] + red[1][tid] + red[2][tid] + red[3][tid];
        partial[(size_t)blockIdx.x*65 + tid] = v;
    }
}

// =================== faithful fp32 LAPACK helpers =========================
__device__ inline float f_sign(float a, float b){
    return (b >= 0.f) ? fabsf(a) : -fabsf(a);     // Fortran SIGN(a,b)
}

__device__ inline float slapy2(float xx, float yy){
#pragma clang fp contract(off)
    float xa = fabsf(xx), ya = fabsf(yy);
    float w = fmaxf(xa, ya), z = fminf(xa, ya);
    if (z == 0.f) return w;
    float q = z / w;
    return w * sqrtf(1.f + q*q);
}

// LAPACK >= 3.10 slartg convention (c >= 0).
__device__ inline void slartg(float f, float g, float* cs, float* sn, float* rr){
#pragma clang fp contract(off)
    const float safmin = 0x1.0p-126f;
    const float safmax = 0x1.0p+126f;
    const float rtmin  = 0x1.0p-63f;
    const float rtmax  = 6.5211589e18f;  // sqrt(safmax/2)
    float f1 = fabsf(f), g1 = fabsf(g);
    if (g == 0.f){ *cs = 1.f; *sn = 0.f; *rr = f; }
    else if (f == 0.f){
        *cs = 0.f;
        *sn = (g >= 0.f) ? 1.f : -1.f;
        *rr = g1;
    } else {
        if (f1 > rtmin && f1 < rtmax && g1 > rtmin && g1 < rtmax){
            float d = sqrtf(f*f + g*g);
            *cs = f1 / d;
            *rr = (f >= 0.f) ? d : -d;
            *sn = g / (*rr);
        } else {
            float u = fminf(safmax, fmaxf(safmin, fmaxf(f1, g1)));
            float fs = f/u, gs = g/u;
            float d = sqrtf(fs*fs + gs*gs);
            *cs = fabsf(fs)/d;
            float r0 = (f >= 0.f) ? d : -d;
            *sn = gs / r0;
            *rr = r0 * u;
        }
    }
}

__device__ inline void slaev2(float a, float b, float c,
                              float* rt1, float* rt2, float* cs1, float* sn1){
#pragma clang fp contract(off)
    float sm = a + c;
    float df = a - c;
    float adf = fabsf(df);
    float tb = b + b;
    float ab = fabsf(tb);
    float acmx, acmn;
    if (fabsf(a) > fabsf(c)){ acmx = a; acmn = c; } else { acmx = c; acmn = a; }
    float rt;
    if (adf > ab){ float q = ab/adf; rt = adf*sqrtf(1.f + q*q); }
    else if (adf < ab){ float q = adf/ab; rt = ab*sqrtf(1.f + q*q); }
    else { rt = ab*sqrtf(2.f); }
    int sgn1;
    if (sm < 0.f){
        *rt1 = 0.5f*(sm - rt); sgn1 = -1;
        *rt2 = (acmx / *rt1)*acmn - (b / *rt1)*b;
    } else if (sm > 0.f){
        *rt1 = 0.5f*(sm + rt); sgn1 = 1;
        *rt2 = (acmx / *rt1)*acmn - (b / *rt1)*b;
    } else {
        *rt1 = 0.5f*rt; *rt2 = -0.5f*rt; sgn1 = 1;
    }
    float cs; int sgn2;
    if (df >= 0.f){ cs = df + rt; sgn2 = 1; }
    else { cs = df - rt; sgn2 = -1; }
    float acs = fabsf(cs);
    if (acs > ab){
        float ct = -tb/cs;
        *sn1 = 1.f/sqrtf(1.f + ct*ct);
        *cs1 = ct * (*sn1);
    } else {
        if (ab == 0.f){ *cs1 = 1.f; *sn1 = 0.f; }
        else {
            float tn = -cs/tb;
            *cs1 = 1.f/sqrtf(1.f + tn*tn);
            *sn1 = tn * (*cs1);
        }
    }
    if (sgn1 == sgn2){
        float tn = *cs1;
        *cs1 = -(*sn1);
        *sn1 = tn;
    }
}

#define A_(i,j) Aa[((j)-1)*10 + ((i)-1)]

// wave-cooperative ssyevd('V','L') n=10; lanes 0..63 of one wave.
// ssytd2: LDS (lane-parallel O(n^2), scalar chain redundant on all lanes).
// ssteqr: dd/ee/wk and Z in lane-distributed REGISTERS (readlane gathers,
//         predicated writes) — identical arithmetic order to LAPACK.
// sormtr: single argmax column.
__device__ void eig10_wave(int lane, float* Aa, float* dd, float* ee,
                           float* tt, float* px, float* vout)
{
#pragma clang fp contract(off)
    const int n = 10;

    // ---------------- ssytd2 (lower) ----------------
    for (int i = 1; i <= n-1; i++){
        float alpha = A_(i+1, i);
        float ssq = 0.f;
        for (int k = i+2; k <= n; k++){ float v = A_(k,i); ssq += v*v; }
        float xnorm = sqrtf(ssq);
        float taui;
        if (xnorm == 0.f){
            taui = 0.f;
        } else {
            float beta = -f_sign(slapy2(alpha, xnorm), alpha);
            taui = (beta - alpha) / beta;
            float sc = 1.f / (alpha - beta);
            for (int k = i+2; k <= n; k++) A_(k,i) *= sc;   // all lanes same value
            alpha = beta;
        }
        ee[i] = alpha;
        if (taui != 0.f){
            A_(i+1, i) = 1.f;
            const int n2 = n - i;
            // parallel ssymv 'L': lane l2 computes px[l2]; contribution order
            // identical to LAPACK's interleaved j-loop.
            if (lane >= 1 && lane <= n2){
                const int l2 = lane;
                float p = 0.f;
                for (int j = 1; j <= l2-1; j++)
                    p = p + (taui * A_(i+j, i)) * A_(i+l2, i+j);
                p = p + (taui * A_(i+l2, i)) * A_(i+l2, i+l2);
                float temp2 = 0.f;
                for (int ii2 = l2+1; ii2 <= n2; ii2++)
                    temp2 = temp2 + A_(i+ii2, i+l2) * A_(i+ii2, i);
                p = p + taui * temp2;
                px[l2] = p;
            }
            // sdot (serial order, redundant on all lanes)
            float dot = 0.f;
            for (int j = 1; j <= n2; j++) dot = dot + px[j] * A_(i+j, i);
            float alpha2 = -0.5f * taui * dot;
            if (lane >= 1 && lane <= n2)
                px[lane] = px[lane] + alpha2 * A_(i+lane, i);
            // parallel ssyr2 'L': lane = column j
            if (lane >= 1 && lane <= n2){
                const int j = lane;
                float xj = A_(i+j, i);
                float yj = px[j];
                if (xj != 0.f || yj != 0.f){
                    float temp1 = -yj;
                    float temp2 = -xj;
                    for (int ii2 = j; ii2 <= n2; ii2++){
                        A_(i+ii2, i+j) = A_(i+ii2, i+j)
                                       + A_(i+ii2, i)*temp1 + px[ii2]*temp2;
                    }
                }
            }
            A_(i+1, i) = ee[i];
        }
        dd[i] = A_(i, i);
        tt[i] = taui;
    }
    dd[n] = A_(n, n);

    // ---------------- load distributed state ----------------
    float dd_r = (lane >= 1 && lane <= n)   ? dd[lane] : 0.f;
    float ee_r = (lane >= 1 && lane <= n-1) ? ee[lane] : 0.f;
    float wkc_r = 0.f, wks_r = 0.f;
    float z[10];           // lane j (1..10) holds Z column j, rows 0..9
    #pragma unroll
    for (int r = 0; r < 10; r++) z[r] = (lane == r+1) ? 1.f : 0.f;

    auto ZROT = [&](int jj, float c, float s){
        #pragma unroll
        for (int r = 0; r < 10; r++){
            float a  = rl(z[r], jj+1);
            float bz = rl(z[r], jj);
            float na = c*a - s*bz;
            float nb = s*a + c*bz;
            z[r] = (lane == jj+1) ? na : ((lane == jj) ? nb : z[r]);
        }
    };

    // ---------------- ssteqr 'I' (register version) ----------------
    const float eps    = 0x1.0p-24f;
    const float eps2   = 0x1.0p-48f;
    const float safmin = 0x1.0p-126f;
    const int nmaxit = n * 30;
    int jtot = 0;
    int l1 = 1;

    while (true){
        if (l1 > n) break;
        if (l1 > 1){ if (lane == l1-1) ee_r = 0.f; }
        int m = n;
        if (l1 <= n-1){
            for (m = l1; m <= n-1; m++){
                float tst = fabsf(rl(ee_r, m));
                if (tst == 0.f) break;
                if (tst <= (sqrtf(fabsf(rl(dd_r, m))) * sqrtf(fabsf(rl(dd_r, m+1)))) * eps){
                    if (lane == m) ee_r = 0.f;
                    break;
                }
            }
        }
        int l = l1;
        int lsv = l;
        int lend = m;
        int lendsv = lend;
        l1 = m + 1;
        if (lend == l) continue;

        float anorm = 0.f;
        for (int k = l; k <= lend; k++)   anorm = fmaxf(anorm, fabsf(rl(dd_r, k)));
        for (int k = l; k <= lend-1; k++) anorm = fmaxf(anorm, fabsf(rl(ee_r, k)));
        if (anorm == 0.f) continue;

        if (fabsf(rl(dd_r, lend)) < fabsf(rl(dd_r, l))){
            lend = lsv;
            l = lendsv;
        }

        if (lend > l){
            // -------- QL --------
            while (true){
                int mq = lend;
                if (l != lend){
                    for (int t2 = l; t2 <= lend-1; t2++){
                        float ev = fabsf(rl(ee_r, t2));
                        if (ev*ev <= (eps2*fabsf(rl(dd_r, t2)))*fabsf(rl(dd_r, t2+1)) + safmin){
                            mq = t2; break;
                        }
                    }
                }
                if (mq < lend){ if (lane == mq) ee_r = 0.f; }
                float p = rl(dd_r, l);
                if (mq == l){
                    l = l + 1;
                    if (l <= lend) continue;
                    break;
                }
                if (mq == l+1){
                    float rt1, rt2, cc, ss;
                    slaev2(rl(dd_r, l), rl(ee_r, l), rl(dd_r, l+1), &rt1, &rt2, &cc, &ss);
                    ZROT(l, cc, ss);
                    if (lane == l)   dd_r = rt1;
                    if (lane == l+1) dd_r = rt2;
                    if (lane == l)   ee_r = 0.f;
                    l += 2;
                    if (l <= lend) continue;
                    break;
                }
                if (jtot == nmaxit) break;
                jtot++;
                float g = (rl(dd_r, l+1) - p) / (2.f * rl(ee_r, l));
                float r0 = slapy2(g, 1.f);
                g = rl(dd_r, mq) - p + (rl(ee_r, l) / (g + f_sign(r0, g)));
                float ss = 1.f, cc = 1.f;
                p = 0.f;
                for (int i2 = mq-1; i2 >= l; i2--){
                    float e2 = rl(ee_r, i2);
                    float ff = ss * e2;
                    float bb = cc * e2;
                    float rr;
                    slartg(g, ff, &cc, &ss, &rr);
                    if (i2 != mq-1){ if (lane == i2+1) ee_r = rr; }
                    g = rl(dd_r, i2+1) - p;
                    rr = (rl(dd_r, i2) - g)*ss + 2.f*cc*bb;
                    p = ss*rr;
                    if (lane == i2+1) dd_r = g + p;
                    g = cc*rr - bb;
                    if (lane == i2){ wkc_r = cc; wks_r = -ss; }
                }
                for (int jj = mq-1; jj >= l; jj--){
                    float ct = rl(wkc_r, jj), st = rl(wks_r, jj);
                    if (ct != 1.f || st != 0.f) ZROT(jj, ct, st);
                }
                if (lane == l) dd_r = dd_r - p;
                if (lane == l) ee_r = g;
            }
        } else {
            // -------- QR --------
            while (true){
                int mq = lend;
                if (l != lend){
                    for (int t2 = l; t2 >= lend+1; t2--){
                        float ev = fabsf(rl(ee_r, t2-1));
                        if (ev*ev <= (eps2*fabsf(rl(dd_r, t2)))*fabsf(rl(dd_r, t2-1)) + safmin){
                            mq = t2; break;
                        }
                    }
                }
                if (mq > lend){ if (lane == mq-1) ee_r = 0.f; }
                float p = rl(dd_r, l);
                if (mq == l){
                    l = l - 1;
                    if (l >= lend) continue;
                    break;
                }
                if (mq == l-1){
                    float rt1, rt2, cc, ss;
                    slaev2(rl(dd_r, l-1), rl(ee_r, l-1), rl(dd_r, l), &rt1, &rt2, &cc, &ss);
                    ZROT(l-1, cc, ss);
                    if (lane == l-1) dd_r = rt1;
                    if (lane == l)   dd_r = rt2;
                    if (lane == l-1) ee_r = 0.f;
                    l -= 2;
                    if (l >= lend) continue;
                    break;
                }
                if (jtot == nmaxit) break;
                jtot++;
                float g = (rl(dd_r, l-1) - p) / (2.f * rl(ee_r, l-1));
                float r0 = slapy2(g, 1.f);
                g = rl(dd_r, mq) - p + (rl(ee_r, l-1) / (g + f_sign(r0, g)));
                float ss = 1.f, cc = 1.f;
                p = 0.f;
                for (int i2 = mq; i2 <= l-1; i2++){
                    float e2 = rl(ee_r, i2);
                    float ff = ss * e2;
                    float bb = cc * e2;
                    float rr;
                    slartg(g, ff, &cc, &ss, &rr);
                    if (i2 != mq){ if (lane == i2-1) ee_r = rr; }
                    g = rl(dd_r, i2) - p;
                    rr = (rl(dd_r, i2+1) - g)*ss + 2.f*cc*bb;
                    p = ss*rr;
                    if (lane == i2) dd_r = g + p;
                    g = cc*rr - bb;
                    if (lane == i2){ wkc_r = cc; wks_r = ss; }
                }
                for (int jj = mq; jj <= l-1; jj++){
                    float ct = rl(wkc_r, jj), st = rl(wks_r, jj);
                    if (ct != 1.f || st != 0.f) ZROT(jj, ct, st);
                }
                if (lane == l)   dd_r = dd_r - p;
                if (lane == l-1) ee_r = g;
            }
        }
        if (jtot < nmaxit) continue;
        break;
    }

    // ---------------- argmax (ascending sort's last == max) ----------------
    int kmax = 1;
    float pmax = rl(dd_r, 1);
    for (int j = 2; j <= n; j++){
        float dj = rl(dd_r, j);
        if (dj > pmax){ pmax = dj; kmax = j; }
    }

    // extract column kmax -> lane-distributed vcol (lane r+1 holds row r+1)
    float vc = 0.f;
    #pragma unroll
    for (int r = 0; r < 10; r++){
        float s = rl(z[r], kmax);
        vc = (lane == r+1) ? s : vc;
    }

    // ---------------- sormtr 'L','L','N' on the single column ------------
    for (int i = n-1; i >= 1; i--){
        float taui = tt[i];
        if (taui != 0.f){
            float s1 = rl(vc, i+1);
            for (int r2 = i+2; r2 <= n; r2++) s1 = s1 + A_(r2, i) * rl(vc, r2);
            s1 = taui * s1;
            if (lane == i+1) vc = vc - s1;
            if (lane >= i+2 && lane <= n) vc = vc - A_(lane, i) * s1;
        }
    }
    if (lane >= 1 && lane <= n) vout[lane-1] = vc;
}

// ======================= Kernel 2: D, eigh, outputs =======================
__global__ __launch_bounds__(64) void k2_eig(
        const float* __restrict__ partial, const float* __restrict__ tmpl,
        float* __restrict__ out, int cblk)
{
    __shared__ float SS[66];
    __shared__ float Aa[100];
    __shared__ float dd[12], ee[12], tt[12], px[12], vout[12];
    const int lane = threadIdx.x;
    const int b = blockIdx.x;

    for (int i = lane; i < 65; i += 64){
        float s = 0.f;
        for (int p = 0; p < cblk; p++)
            s += partial[((size_t)b*cblk + p)*65 + i];
        SS[i] = s;
    }
    __syncthreads();

    // D[t][s] = S2 - S1 S1^T / C (exactly symmetric), col-major in Aa
    for (int idx = lane; idx < 100; idx += 64){
        int t = idx % 10, s2 = idx / 10;
        int lo = t < s2 ? t : s2, hi = t < s2 ? s2 : t;
        int pk = 10*lo - (lo*(lo-1))/2 + (hi - lo);
        Aa[s2*10 + t] = SS[10 + pk] - SS[t]*SS[s2]*(1.0f/2048.0f);
    }
    __syncthreads();

    eig10_wave(lane, Aa, dd, ee, tt, px, vout);
    __syncthreads();

    if (lane >= 1 && lane <= NTMP)
        out[(size_t)NB*NHW + (size_t)b*NTMP + (lane-1)] = vout[lane-1];

    for (int i = lane; i < NHW; i += 64){
        float m2 = 0.f;
        #pragma unroll
        for (int t = 0; t < NTMP; t++) m2 += vout[t] * tmpl[t*NHW + i];
        out[(size_t)b*NHW + i] = m2;
    }
}

// ============================== launcher ==================================
extern "C" void kernel_launch(void* const* d_in, const int* in_sizes, int n_in,
                              void* d_out, int out_size, void* d_ws, size_t ws_size,
                              hipStream_t stream)
{
    const float* x    = (const float*)d_in[0];
    const float* tmpl = (const float*)d_in[1];
    float* out = (float*)d_out;
    float* partial = (float*)d_ws;

    if (ws_size >= (size_t)NB*8*65*sizeof(float)){
        k1_partials<8><<<dim3(NB*8), dim3(256), 0, stream>>>(x, tmpl, partial);
        k2_eig<<<dim3(NB), dim3(64), 0, stream>>>(partial, tmpl, out, 8);
    } else if (ws_size >= (size_t)NB*4*65*sizeof(float)){
        k1_partials<4><<<dim3(NB*4), dim3(256), 0, stream>>>(x, tmpl, partial);
        k2_eig<<<dim3(NB), dim3(64), 0, stream>>>(partial, tmpl, out, 4);
    } else {
        k1_partials<1><<<dim3(NB), dim3(256), 0, stream>>>(x, tmpl, partial);
        k2_eig<<<dim3(NB), dim3(64), 0, stream>>>(partial, tmpl, out, 1);
    }
}

// Round 5
// 136.530 us; speedup vs baseline: 2.0711x; 2.0711x over previous
//
#include <hip/hip_runtime.h>
#include <math.h>

// PCATemplateMap: x (64,2048,19,19) f32, templates (10,19,19) f32
// outputs: mask (64,1,19,19) then v (64,10), concatenated flat.
//
//  k1 (thread-per-channel, R2 structure + MLP): templates broadcast from LDS
//     (wave-uniform b128), x streamed 16B/thread with deep unroll, 2 blocks/CU;
//     per-wave LDS-transpose reduce -> 65 partial sums per block -> d_ws.
//  k2: one wave per batch. D = S2 - S1 S1^T / C, LAPACK ssyevd port
//     (ssytd2 + ssteqr 'I' in lane-distributed registers + argmax +
//     single-column sormtr) with SAME branch structure/conventions but
//     fast rcp/rsq arithmetic (sign-stable, ~1e-6 perturbations).

#define NB   64
#define NC   2048
#define NHW  361
#define NTMP 10

struct f4 { float x, y, z, w; };
__device__ inline f4 load4u(const float* p){
    f4 r;
    __builtin_memcpy(&r, p, 16);
    return r;
}

__device__ inline float rl(float v, int i){
    return __int_as_float(__builtin_amdgcn_readlane(__float_as_int(v), i));
}

// fast reciprocal / rsqrt (~1 ulp) — only perturbs arithmetic, not branches
__device__ inline float frcp(float x){
#if __has_builtin(__builtin_amdgcn_rcpf)
    return __builtin_amdgcn_rcpf(x);
#else
    return 1.0f / x;
#endif
}
__device__ inline float frsq(float x){
#if __has_builtin(__builtin_amdgcn_rsqf)
    return __builtin_amdgcn_rsqf(x);
#else
    return 1.0f / sqrtf(x);
#endif
}
__device__ inline float fdivf(float a, float b){ return a * frcp(b); }

// ======================= Kernel 1: partial S1/S2 ==========================
// grid NB*CBLK x 256 threads. NCPT = channels per thread.
template<int CBLK>
__global__ __launch_bounds__(256) void k1_partials(
        const float* __restrict__ x, const float* __restrict__ tmpl,
        float* __restrict__ partial)
{
    constexpr int NCPT = NC / (CBLK * 256);
    __shared__ __align__(16) float Tl[NTMP][364];   // 1456B row stride (16B mult)
    __shared__ float QL[4][64][13];
    __shared__ float red[4][66];
    const int tid = threadIdx.x, lane = tid & 63, wid = tid >> 6;

    for (int idx = tid; idx < NTMP*364; idx += 256){
        int t = idx / 364, i = idx - t*364;
        Tl[t][i] = (i < NHW) ? tmpl[t*NHW + i] : 0.f;
    }
    __syncthreads();

    const int b  = blockIdx.x / CBLK;
    const int cb = blockIdx.x % CBLK;

    const float* xr[NCPT];
    #pragma unroll
    for (int s = 0; s < NCPT; s++)
        xr[s] = x + ((size_t)b*NC + (size_t)cb*(256*NCPT) + s*256 + tid)*NHW;

    float acc[NCPT][NTMP];
    #pragma unroll
    for (int s = 0; s < NCPT; s++)
        #pragma unroll
        for (int t = 0; t < NTMP; t++) acc[s][t] = 0.f;

    // 90 chunks of 4 floats + scalar tail (361 = 90*4 + 1)
    #pragma unroll 10
    for (int ch = 0; ch < 90; ch++){
        f4 xv[NCPT];
        #pragma unroll
        for (int s = 0; s < NCPT; s++) xv[s] = load4u(xr[s] + ch*4);
        #pragma unroll
        for (int t = 0; t < NTMP; t++){
            const f4 tv = *reinterpret_cast<const f4*>(&Tl[t][ch*4]); // broadcast
            #pragma unroll
            for (int s = 0; s < NCPT; s++)
                acc[s][t] += xv[s].x*tv.x + xv[s].y*tv.y
                           + xv[s].z*tv.z + xv[s].w*tv.w;
        }
    }
    #pragma unroll
    for (int s = 0; s < NCPT; s++){
        const float xt = xr[s][360];
        #pragma unroll
        for (int t = 0; t < NTMP; t++) acc[s][t] += xt * Tl[t][360];
    }

    // ---- per-wave S1/S2 via LDS transpose (R2 pattern, in-order DS) ------
    // lane < 55: S2 pair k=lane -> (tA,uA); lanes 55..63: S1 t=lane-55;
    // lane 54 (pair 9,9) also accumulates S1 t=9.
    int tA, uA;
    if (lane < 55){
        int k = lane, t = 0;
        while (k >= NTMP - t){ k -= NTMP - t; t++; }
        tA = t; uA = t + k;
    } else { tA = lane - 55; uA = tA; }

    float sv = 0.f, s1v = 0.f;
    #pragma unroll
    for (int s = 0; s < NCPT; s++){
        #pragma unroll
        for (int t = 0; t < NTMP; t++) QL[wid][lane][t] = acc[s][t];
        #pragma unroll 8
        for (int c = 0; c < 64; c++){
            float qt = QL[wid][c][tA];
            float qu = QL[wid][c][uA];
            sv  += qt*qu;
            s1v += qt;
        }
    }
    if (lane < 55) red[wid][10 + lane] = sv;
    else           red[wid][lane - 55] = s1v;
    if (lane == 54) red[wid][9] = s1v;
    __syncthreads();
    if (tid < 65){
        float v = red[0][tid] + red[1][tid] + red[2][tid] + red[3][tid];
        partial[(size_t)blockIdx.x*65 + tid] = v;
    }
}

// =================== LAPACK helpers (fast arithmetic) =====================
__device__ inline float f_sign(float a, float b){
    return (b >= 0.f) ? fabsf(a) : -fabsf(a);     // Fortran SIGN(a,b)
}

__device__ inline float slapy2(float xx, float yy){
#pragma clang fp contract(off)
    float xa = fabsf(xx), ya = fabsf(yy);
    float w = fmaxf(xa, ya), z = fminf(xa, ya);
    if (z == 0.f) return w;
    float q = fdivf(z, w);
    return w * sqrtf(1.f + q*q);
}

// LAPACK >= 3.10 slartg convention (c >= 0); same branches, rsq arithmetic.
__device__ inline void slartg(float f, float g, float* cs, float* sn, float* rr){
#pragma clang fp contract(off)
    const float safmin = 0x1.0p-126f;
    const float safmax = 0x1.0p+126f;
    const float rtmin  = 0x1.0p-63f;
    const float rtmax  = 6.5211589e18f;  // sqrt(safmax/2)
    float f1 = fabsf(f), g1 = fabsf(g);
    if (g == 0.f){ *cs = 1.f; *sn = 0.f; *rr = f; }
    else if (f == 0.f){
        *cs = 0.f;
        *sn = (g >= 0.f) ? 1.f : -1.f;
        *rr = g1;
    } else {
        if (f1 > rtmin && f1 < rtmax && g1 > rtmin && g1 < rtmax){
            float rr2 = f*f + g*g;
            float inv = frsq(rr2);
            float d   = rr2 * inv;            // sqrt(f^2+g^2)
            float sgn = (f >= 0.f) ? 1.f : -1.f;
            *cs = f1 * inv;
            *rr = sgn * d;
            *sn = g * inv * sgn;
        } else {
            float u = fminf(safmax, fmaxf(safmin, fmaxf(f1, g1)));
            float fs = fdivf(f, u), gs = fdivf(g, u);
            float rr2 = fs*fs + gs*gs;
            float inv = frsq(rr2);
            float d   = rr2 * inv;
            *cs = fabsf(fs) * inv;
            float r0 = (f >= 0.f) ? d : -d;
            *sn = fdivf(gs, r0);
            *rr = r0 * u;
        }
    }
}

__device__ inline void slaev2(float a, float b, float c,
                              float* rt1, float* rt2, float* cs1, float* sn1){
#pragma clang fp contract(off)
    float sm = a + c;
    float df = a - c;
    float adf = fabsf(df);
    float tb = b + b;
    float ab = fabsf(tb);
    float acmx, acmn;
    if (fabsf(a) > fabsf(c)){ acmx = a; acmn = c; } else { acmx = c; acmn = a; }
    float rt;
    if (adf > ab){ float q = fdivf(ab, adf); rt = adf*sqrtf(1.f + q*q); }
    else if (adf < ab){ float q = fdivf(adf, ab); rt = ab*sqrtf(1.f + q*q); }
    else { rt = ab*sqrtf(2.f); }
    int sgn1;
    if (sm < 0.f){
        *rt1 = 0.5f*(sm - rt); sgn1 = -1;
        float inv1 = frcp(*rt1);
        *rt2 = (acmx*inv1)*acmn - (b*inv1)*b;
    } else if (sm > 0.f){
        *rt1 = 0.5f*(sm + rt); sgn1 = 1;
        float inv1 = frcp(*rt1);
        *rt2 = (acmx*inv1)*acmn - (b*inv1)*b;
    } else {
        *rt1 = 0.5f*rt; *rt2 = -0.5f*rt; sgn1 = 1;
    }
    float cs; int sgn2;
    if (df >= 0.f){ cs = df + rt; sgn2 = 1; }
    else { cs = df - rt; sgn2 = -1; }
    float acs = fabsf(cs);
    if (acs > ab){
        float ct = fdivf(-tb, cs);
        *sn1 = frsq(1.f + ct*ct);
        *cs1 = ct * (*sn1);
    } else {
        if (ab == 0.f){ *cs1 = 1.f; *sn1 = 0.f; }
        else {
            float tn = fdivf(-cs, tb);
            *cs1 = frsq(1.f + tn*tn);
            *sn1 = tn * (*cs1);
        }
    }
    if (sgn1 == sgn2){
        float tn = *cs1;
        *cs1 = -(*sn1);
        *sn1 = tn;
    }
}

#define A_(i,j) Aa[((j)-1)*10 + ((i)-1)]

// wave-cooperative ssyevd('V','L') n=10; lanes 0..63 of one wave.
__device__ void eig10_wave(int lane, float* Aa, float* dd, float* ee,
                           float* tt, float* px, float* vout)
{
#pragma clang fp contract(off)
    const int n = 10;

    // ---------------- ssytd2 (lower) ----------------
    for (int i = 1; i <= n-1; i++){
        float alpha = A_(i+1, i);
        float ssq = 0.f;
        for (int k = i+2; k <= n; k++){ float v = A_(k,i); ssq += v*v; }
        float xnorm = sqrtf(ssq);
        float taui;
        if (xnorm == 0.f){
            taui = 0.f;
        } else {
            float beta = -f_sign(slapy2(alpha, xnorm), alpha);
            taui = fdivf(beta - alpha, beta);
            float sc = frcp(alpha - beta);
            for (int k = i+2; k <= n; k++) A_(k,i) *= sc;   // all lanes same value
            alpha = beta;
        }
        ee[i] = alpha;
        if (taui != 0.f){
            A_(i+1, i) = 1.f;
            const int n2 = n - i;
            if (lane >= 1 && lane <= n2){
                const int l2 = lane;
                float p = 0.f;
                for (int j = 1; j <= l2-1; j++)
                    p = p + (taui * A_(i+j, i)) * A_(i+l2, i+j);
                p = p + (taui * A_(i+l2, i)) * A_(i+l2, i+l2);
                float temp2 = 0.f;
                for (int ii2 = l2+1; ii2 <= n2; ii2++)
                    temp2 = temp2 + A_(i+ii2, i+l2) * A_(i+ii2, i);
                p = p + taui * temp2;
                px[l2] = p;
            }
            float dot = 0.f;
            for (int j = 1; j <= n2; j++) dot = dot + px[j] * A_(i+j, i);
            float alpha2 = -0.5f * taui * dot;
            if (lane >= 1 && lane <= n2)
                px[lane] = px[lane] + alpha2 * A_(i+lane, i);
            if (lane >= 1 && lane <= n2){
                const int j = lane;
                float xj = A_(i+j, i);
                float yj = px[j];
                if (xj != 0.f || yj != 0.f){
                    float temp1 = -yj;
                    float temp2 = -xj;
                    for (int ii2 = j; ii2 <= n2; ii2++){
                        A_(i+ii2, i+j) = A_(i+ii2, i+j)
                                       + A_(i+ii2, i)*temp1 + px[ii2]*temp2;
                    }
                }
            }
            A_(i+1, i) = ee[i];
        }
        dd[i] = A_(i, i);
        tt[i] = taui;
    }
    dd[n] = A_(n, n);

    // ---------------- lane-distributed state ----------------
    float dd_r = (lane >= 1 && lane <= n)   ? dd[lane] : 0.f;
    float ee_r = (lane >= 1 && lane <= n-1) ? ee[lane] : 0.f;
    float wkc_r = 0.f, wks_r = 0.f;
    float z[10];           // lane j (1..10) holds Z column j, rows 0..9
    #pragma unroll
    for (int r = 0; r < 10; r++) z[r] = (lane == r+1) ? 1.f : 0.f;

    auto ZROT = [&](int jj, float c, float s){
        const bool isA = (lane == jj+1), isB = (lane == jj);
        #pragma unroll
        for (int r = 0; r < 10; r++){
            float a  = rl(z[r], jj+1);
            float bz = rl(z[r], jj);
            float nv = isA ? (c*a - s*bz) : (s*a + c*bz);
            z[r] = (isA || isB) ? nv : z[r];
        }
    };

    // ---------------- ssteqr 'I' (register version) ----------------
    const float eps    = 0x1.0p-24f;
    const float eps2   = 0x1.0p-48f;
    const float safmin = 0x1.0p-126f;
    const int nmaxit = n * 30;
    int jtot = 0;
    int l1 = 1;

    while (true){
        if (l1 > n) break;
        if (l1 > 1){ if (lane == l1-1) ee_r = 0.f; }
        int m = n;
        if (l1 <= n-1){
            for (m = l1; m <= n-1; m++){
                float tst = fabsf(rl(ee_r, m));
                if (tst == 0.f) break;
                if (tst <= (sqrtf(fabsf(rl(dd_r, m))) * sqrtf(fabsf(rl(dd_r, m+1)))) * eps){
                    if (lane == m) ee_r = 0.f;
                    break;
                }
            }
        }
        int l = l1;
        int lsv = l;
        int lend = m;
        int lendsv = lend;
        l1 = m + 1;
        if (lend == l) continue;

        float anorm = 0.f;
        for (int k = l; k <= lend; k++)   anorm = fmaxf(anorm, fabsf(rl(dd_r, k)));
        for (int k = l; k <= lend-1; k++) anorm = fmaxf(anorm, fabsf(rl(ee_r, k)));
        if (anorm == 0.f) continue;

        if (fabsf(rl(dd_r, lend)) < fabsf(rl(dd_r, l))){
            lend = lsv;
            l = lendsv;
        }

        if (lend > l){
            // -------- QL --------
            while (true){
                int mq = lend;
                if (l != lend){
                    for (int t2 = l; t2 <= lend-1; t2++){
                        float ev = fabsf(rl(ee_r, t2));
                        if (ev*ev <= (eps2*fabsf(rl(dd_r, t2)))*fabsf(rl(dd_r, t2+1)) + safmin){
                            mq = t2; break;
                        }
                    }
                }
                if (mq < lend){ if (lane == mq) ee_r = 0.f; }
                float p = rl(dd_r, l);
                if (mq == l){
                    l = l + 1;
                    if (l <= lend) continue;
                    break;
                }
                if (mq == l+1){
                    float rt1, rt2, cc, ss;
                    slaev2(rl(dd_r, l), rl(ee_r, l), rl(dd_r, l+1), &rt1, &rt2, &cc, &ss);
                    ZROT(l, cc, ss);
                    if (lane == l)   dd_r = rt1;
                    if (lane == l+1) dd_r = rt2;
                    if (lane == l)   ee_r = 0.f;
                    l += 2;
                    if (l <= lend) continue;
                    break;
                }
                if (jtot == nmaxit) break;
                jtot++;
                float g = fdivf(rl(dd_r, l+1) - p, 2.f * rl(ee_r, l));
                float r0 = slapy2(g, 1.f);
                g = rl(dd_r, mq) - p + fdivf(rl(ee_r, l), g + f_sign(r0, g));
                float ss = 1.f, cc = 1.f;
                p = 0.f;
                for (int i2 = mq-1; i2 >= l; i2--){
                    float e2 = rl(ee_r, i2);
                    float ff = ss * e2;
                    float bb = cc * e2;
                    float rr;
                    slartg(g, ff, &cc, &ss, &rr);
                    if (i2 != mq-1){ if (lane == i2+1) ee_r = rr; }
                    g = rl(dd_r, i2+1) - p;
                    rr = (rl(dd_r, i2) - g)*ss + 2.f*cc*bb;
                    p = ss*rr;
                    if (lane == i2+1) dd_r = g + p;
                    g = cc*rr - bb;
                    if (lane == i2){ wkc_r = cc; wks_r = -ss; }
                }
                for (int jj = mq-1; jj >= l; jj--){
                    float ct = rl(wkc_r, jj), st = rl(wks_r, jj);
                    if (ct != 1.f || st != 0.f) ZROT(jj, ct, st);
                }
                if (lane == l) dd_r = dd_r - p;
                if (lane == l) ee_r = g;
            }
        } else {
            // -------- QR --------
            while (true){
                int mq = lend;
                if (l != lend){
                    for (int t2 = l; t2 >= lend+1; t2--){
                        float ev = fabsf(rl(ee_r, t2-1));
                        if (ev*ev <= (eps2*fabsf(rl(dd_r, t2)))*fabsf(rl(dd_r, t2-1)) + safmin){
                            mq = t2; break;
                        }
                    }
                }
                if (mq > lend){ if (lane == mq-1) ee_r = 0.f; }
                float p = rl(dd_r, l);
                if (mq == l){
                    l = l - 1;
                    if (l >= lend) continue;
                    break;
                }
                if (mq == l-1){
                    float rt1, rt2, cc, ss;
                    slaev2(rl(dd_r, l-1), rl(ee_r, l-1), rl(dd_r, l), &rt1, &rt2, &cc, &ss);
                    ZROT(l-1, cc, ss);
                    if (lane == l-1) dd_r = rt1;
                    if (lane == l)   dd_r = rt2;
                    if (lane == l-1) ee_r = 0.f;
                    l -= 2;
                    if (l >= lend) continue;
                    break;
                }
                if (jtot == nmaxit) break;
                jtot++;
                float g = fdivf(rl(dd_r, l-1) - p, 2.f * rl(ee_r, l-1));
                float r0 = slapy2(g, 1.f);
                g = rl(dd_r, mq) - p + fdivf(rl(ee_r, l-1), g + f_sign(r0, g));
                float ss = 1.f, cc = 1.f;
                p = 0.f;
                for (int i2 = mq; i2 <= l-1; i2++){
                    float e2 = rl(ee_r, i2);
                    float ff = ss * e2;
                    float bb = cc * e2;
                    float rr;
                    slartg(g, ff, &cc, &ss, &rr);
                    if (i2 != mq){ if (lane == i2-1) ee_r = rr; }
                    g = rl(dd_r, i2) - p;
                    rr = (rl(dd_r, i2+1) - g)*ss + 2.f*cc*bb;
                    p = ss*rr;
                    if (lane == i2) dd_r = g + p;
                    g = cc*rr - bb;
                    if (lane == i2){ wkc_r = cc; wks_r = ss; }
                }
                for (int jj = mq; jj <= l-1; jj++){
                    float ct = rl(wkc_r, jj), st = rl(wks_r, jj);
                    if (ct != 1.f || st != 0.f) ZROT(jj, ct, st);
                }
                if (lane == l)   dd_r = dd_r - p;
                if (lane == l-1) ee_r = g;
            }
        }
        if (jtot < nmaxit) continue;
        break;
    }

    // ---------------- argmax (ascending sort's last == max) ----------------
    int kmax = 1;
    float pmax = rl(dd_r, 1);
    for (int j = 2; j <= n; j++){
        float dj = rl(dd_r, j);
        if (dj > pmax){ pmax = dj; kmax = j; }
    }

    // extract column kmax -> lane-distributed vcol (lane r+1 holds row r+1)
    float vc = 0.f;
    #pragma unroll
    for (int r = 0; r < 10; r++){
        float s = rl(z[r], kmax);
        vc = (lane == r+1) ? s : vc;
    }

    // ---------------- sormtr 'L','L','N' on the single column ------------
    for (int i = n-1; i >= 1; i--){
        float taui = tt[i];
        if (taui != 0.f){
            float s1 = rl(vc, i+1);
            for (int r2 = i+2; r2 <= n; r2++) s1 = s1 + A_(r2, i) * rl(vc, r2);
            s1 = taui * s1;
            if (lane == i+1) vc = vc - s1;
            if (lane >= i+2 && lane <= n) vc = vc - A_(lane, i) * s1;
        }
    }
    if (lane >= 1 && lane <= n) vout[lane-1] = vc;
}

// ======================= Kernel 2: D, eigh, outputs =======================
__global__ __launch_bounds__(64) void k2_eig(
        const float* __restrict__ partial, const float* __restrict__ tmpl,
        float* __restrict__ out, int cblk)
{
    __shared__ float SS[66];
    __shared__ float Aa[100];
    __shared__ float dd[12], ee[12], tt[12], px[12], vout[12];
    const int lane = threadIdx.x;
    const int b = blockIdx.x;

    for (int i = lane; i < 65; i += 64){
        float s = 0.f;
        for (int p = 0; p < cblk; p++)
            s += partial[((size_t)b*cblk + p)*65 + i];
        SS[i] = s;
    }
    __syncthreads();

    // D[t][s] = S2 - S1 S1^T / C (exactly symmetric), col-major in Aa
    for (int idx = lane; idx < 100; idx += 64){
        int t = idx % 10, s2 = idx / 10;
        int lo = t < s2 ? t : s2, hi = t < s2 ? s2 : t;
        int pk = 10*lo - (lo*(lo-1))/2 + (hi - lo);
        Aa[s2*10 + t] = SS[10 + pk] - SS[t]*SS[s2]*(1.0f/2048.0f);
    }
    __syncthreads();

    eig10_wave(lane, Aa, dd, ee, tt, px, vout);
    __syncthreads();

    if (lane >= 1 && lane <= NTMP)
        out[(size_t)NB*NHW + (size_t)b*NTMP + (lane-1)] = vout[lane-1];

    for (int i = lane; i < NHW; i += 64){
        float m2 = 0.f;
        #pragma unroll
        for (int t = 0; t < NTMP; t++) m2 += vout[t] * tmpl[t*NHW + i];
        out[(size_t)b*NHW + i] = m2;
    }
}

// ============================== launcher ==================================
extern "C" void kernel_launch(void* const* d_in, const int* in_sizes, int n_in,
                              void* d_out, int out_size, void* d_ws, size_t ws_size,
                              hipStream_t stream)
{
    const float* x    = (const float*)d_in[0];
    const float* tmpl = (const float*)d_in[1];
    float* out = (float*)d_out;
    float* partial = (float*)d_ws;

    if (ws_size >= (size_t)NB*8*65*sizeof(float)){
        k1_partials<8><<<dim3(NB*8), dim3(256), 0, stream>>>(x, tmpl, partial);
        k2_eig<<<dim3(NB), dim3(64), 0, stream>>>(partial, tmpl, out, 8);
    } else if (ws_size >= (size_t)NB*4*65*sizeof(float)){
        k1_partials<4><<<dim3(NB*4), dim3(256), 0, stream>>>(x, tmpl, partial);
        k2_eig<<<dim3(NB), dim3(64), 0, stream>>>(partial, tmpl, out, 4);
    } else {
        k1_partials<1><<<dim3(NB), dim3(256), 0, stream>>>(x, tmpl, partial);
        k2_eig<<<dim3(NB), dim3(64), 0, stream>>>(partial, tmpl, out, 1);
    }
}